// Round 11
// baseline (391.084 us; speedup 1.0000x reference)
//
#include <hip/hip_runtime.h>

#define NU 100000
#define NI 200000
#define NN 300000
#define NNZE 1200000
#define D 64
#define OS 256   // (L+1)*D output row stride

typedef __attribute__((ext_vector_type(8))) short s16x8;
typedef __attribute__((ext_vector_type(4))) float f32x4;

__device__ __forceinline__ float bf2f(unsigned short u) {
    return __uint_as_float(((unsigned int)u) << 16);
}
__device__ __forceinline__ unsigned short f2bf(float f) {
    unsigned int u = __float_as_uint(f);
    u = (u + 0x7FFF + ((u >> 16) & 1)) >> 16;   // RNE
    return (unsigned short)u;
}

// ---------------- concat -> out chunk0 (fp32, nt) + ebf (bf16 activation) ----
__global__ void k_concat(const float* __restrict__ ue, const float* __restrict__ ie,
                         float* __restrict__ out, unsigned short* __restrict__ ebf) {
    int idx = blockIdx.x * blockDim.x + threadIdx.x;
    if (idx >= NN * 16) return;
    int n = idx >> 4, c = idx & 15;
    float4 v;
    if (n < NU) v = ((const float4*)(ue + (size_t)n * D))[c];
    else        v = ((const float4*)(ie + (size_t)(n - NU) * D))[c];
    f32x4 vv = {v.x, v.y, v.z, v.w};
    __builtin_nontemporal_store(vv, (f32x4*)(out + (size_t)n * OS) + c);
    ushort4 b;
    b.x = f2bf(v.x); b.y = f2bf(v.y); b.z = f2bf(v.z); b.w = f2bf(v.w);
    *(ushort4*)(ebf + (size_t)n * D + c * 4) = b;
}

// ---------------- CSR build ----------------
__global__ void k_hist(const int* __restrict__ rows, int* __restrict__ cnt) {
    int e = blockIdx.x * blockDim.x + threadIdx.x;
    if (e < NNZE) atomicAdd(&cnt[rows[e]], 1);
}

__global__ void k_scan1(const int* __restrict__ cnt, int* __restrict__ rowptr,
                        int* __restrict__ bsum) {
    __shared__ int s[1024];
    int t = threadIdx.x, g = blockIdx.x * 1024 + t;
    int x = (g < NN) ? cnt[g] : 0;
    s[t] = x;
    __syncthreads();
    for (int off = 1; off < 1024; off <<= 1) {
        int y = (t >= off) ? s[t - off] : 0;
        __syncthreads();
        s[t] += y;
        __syncthreads();
    }
    if (g < NN) rowptr[g + 1] = s[t];
    if (t == 1023) bsum[blockIdx.x] = s[1023];
}

__global__ void k_scan2(int* __restrict__ bsum, int nb) {
    __shared__ int s[512];
    int t = threadIdx.x;
    int x = (t < nb) ? bsum[t] : 0;
    s[t] = x;
    __syncthreads();
    for (int off = 1; off < 512; off <<= 1) {
        int y = (t >= off) ? s[t - off] : 0;
        __syncthreads();
        s[t] += y;
        __syncthreads();
    }
    if (t < nb) bsum[t] = s[t];
}

__global__ void k_scan3(int* __restrict__ rowptr, const int* __restrict__ bsum,
                        int* __restrict__ cur) {
    int t = threadIdx.x, g = blockIdx.x * 1024 + t;
    if (g < NN) {
        int off = (blockIdx.x > 0) ? bsum[blockIdx.x - 1] : 0;
        int v = rowptr[g + 1] + off;
        rowptr[g + 1] = v;
        if (g + 1 < NN) cur[g + 1] = v;
    }
    if (g == 0) { rowptr[0] = 0; cur[0] = 0; }
}

__global__ void k_scatter(const int* __restrict__ rows, const int* __restrict__ cols,
                          const float* __restrict__ vals, int* __restrict__ cur,
                          long long* __restrict__ ecv) {
    int e = blockIdx.x * blockDim.x + threadIdx.x;
    if (e >= NNZE) return;
    int r = rows[e];
    int pos = atomicAdd(&cur[r], 1);
    unsigned long long packed = (unsigned int)cols[e]
        | ((unsigned long long)(unsigned int)__float_as_int(vals[e]) << 32);
    ecv[pos] = (long long)packed;
}

// ---------------- CSR SpMM: 16 lanes/row, 8 gathers in flight ----------------
__global__ __launch_bounds__(256) void k_spmm(
    const int* __restrict__ rowptr, const long long* __restrict__ ecv,
    const unsigned short* __restrict__ ebf, unsigned short* __restrict__ sbf) {
    int t = blockIdx.x * blockDim.x + threadIdx.x;
    int g = t >> 4, lane = t & 15;
    if (g >= NN) return;
    int beg = rowptr[g], end = rowptr[g + 1];
    float a0 = 0.f, a1 = 0.f, a2 = 0.f, a3 = 0.f;
    for (int i = beg; i < end; i += 8) {
        // 8 predicated edge loads (off -> c=0, v=0: zero contribution)
        unsigned long long e[8];
        e[0] = (unsigned long long)ecv[i];
        #pragma unroll
        for (int k = 1; k < 8; k++)
            e[k] = (i + k < end) ? (unsigned long long)ecv[i + k] : 0ull;
        // 8 gathers in flight
        ushort4 gg[8];
        float v[8];
        #pragma unroll
        for (int k = 0; k < 8; k++) {
            int c = (int)(e[k] & 0xFFFFFFFFu);
            v[k] = __int_as_float((int)(e[k] >> 32));
            gg[k] = *(const ushort4*)(ebf + (size_t)c * D + lane * 4);
        }
        #pragma unroll
        for (int k = 0; k < 8; k++) {
            a0 += v[k] * bf2f(gg[k].x);
            a1 += v[k] * bf2f(gg[k].y);
            a2 += v[k] * bf2f(gg[k].z);
            a3 += v[k] * bf2f(gg[k].w);
        }
    }
    ushort4 r;
    r.x = f2bf(a0); r.y = f2bf(a1); r.z = f2bf(a2); r.w = f2bf(a3);
    *(ushort4*)(sbf + (size_t)g * D + lane * 4) = r;
}

// ---------------- MFMA dense + leakyrelu + normalize + ebf update ------------
__global__ __launch_bounds__(256) void k_dense(
    const unsigned short* __restrict__ sbf, unsigned short* __restrict__ ebf,
    const float* __restrict__ Wc, const float* __restrict__ bc,
    const float* __restrict__ We, const float* __restrict__ be,
    float* __restrict__ outN) {
    __shared__ unsigned short sWT[2][64 * 64];  // W^T [n][k] bf16, XOR-swizzled

    int tid = threadIdx.x;
    int n0 = blockIdx.x * 64;

    #pragma unroll
    for (int m = 0; m < 2; m++) {
        const float* W = m ? We : Wc;
        int base = tid * 16;
        int k = base >> 6, n = base & 63;
        #pragma unroll
        for (int i = 0; i < 4; i++) {
            float4 v = *(const float4*)(W + k * 64 + n + i * 4);
            #pragma unroll
            for (int j = 0; j < 4; j++) {
                int col = n + i * 4 + j;
                int byteoff = (col * 128 + k * 2) ^ ((col & 7) << 4);
                float fv = (j == 0) ? v.x : (j == 1) ? v.y : (j == 2) ? v.z : v.w;
                *(unsigned short*)((char*)&sWT[m][0] + byteoff) = f2bf(fv);
            }
        }
    }

    int wid = tid >> 6, lane = tid & 63;
    int lg = lane >> 4, lr = lane & 15;

    int rowA = n0 + wid * 16 + lr;
    int rowAc = rowA < NN ? rowA : NN - 1;
    size_t abase = (size_t)rowAc * D;
    s16x8 sf[2], ef[2], wf[2];
    sf[0] = *(const s16x8*)(sbf + abase + lg * 8);
    sf[1] = *(const s16x8*)(sbf + abase + 32 + lg * 8);
    ef[0] = *(const s16x8*)(ebf + abase + lg * 8);
    ef[1] = *(const s16x8*)(ebf + abase + 32 + lg * 8);
    #pragma unroll
    for (int kb = 0; kb < 2; kb++) {
        #pragma unroll
        for (int j = 0; j < 8; j++) {
            float p = bf2f((unsigned short)sf[kb][j]) * bf2f((unsigned short)ef[kb][j]);
            wf[kb][j] = (short)f2bf(p);
        }
    }

    f32x4 acc[4];
    #pragma unroll
    for (int c = 0; c < 4; c++) {
        float bj = bc[c * 16 + lr] + be[c * 16 + lr];
        acc[c] = (f32x4){bj, bj, bj, bj};
    }

    __syncthreads();

    #pragma unroll
    for (int c = 0; c < 4; c++) {
        #pragma unroll
        for (int kb = 0; kb < 2; kb++) {
            int row = c * 16 + lr;
            int byteoff = (row * 128 + (kb * 32 + lg * 8) * 2) ^ ((row & 7) << 4);
            s16x8 bWc = *(const s16x8*)((const char*)&sWT[0][0] + byteoff);
            s16x8 bWe = *(const s16x8*)((const char*)&sWT[1][0] + byteoff);
            acc[c] = __builtin_amdgcn_mfma_f32_16x16x32_bf16(sf[kb], bWc, acc[c], 0, 0, 0);
            acc[c] = __builtin_amdgcn_mfma_f32_16x16x32_bf16(wf[kb], bWe, acc[c], 0, 0, 0);
        }
    }

    float o[4][4];
    float ssq[4] = {0.f, 0.f, 0.f, 0.f};
    #pragma unroll
    for (int c = 0; c < 4; c++) {
        #pragma unroll
        for (int r = 0; r < 4; r++) {
            float x = acc[c][r];
            float y = (x > 0.f) ? x : 0.2f * x;
            o[c][r] = y;
            ssq[r] += y * y;
        }
    }
    #pragma unroll
    for (int r = 0; r < 4; r++) {
        ssq[r] += __shfl_xor(ssq[r], 1);
        ssq[r] += __shfl_xor(ssq[r], 2);
        ssq[r] += __shfl_xor(ssq[r], 4);
        ssq[r] += __shfl_xor(ssq[r], 8);
    }
    #pragma unroll
    for (int r = 0; r < 4; r++) {
        int row = n0 + wid * 16 + lg * 4 + r;
        if (row < NN) {
            float sc = 1.0f / fmaxf(sqrtf(ssq[r]), 1e-12f);
            #pragma unroll
            for (int c = 0; c < 4; c++) {
                __builtin_nontemporal_store(o[c][r] * sc,
                                            &outN[(size_t)row * OS + c * 16 + lr]);
                ebf[(size_t)row * D + c * 16 + lr] = f2bf(o[c][r]);
            }
        }
    }
}

extern "C" void kernel_launch(void* const* d_in, const int* in_sizes, int n_in,
                              void* d_out, int out_size, void* d_ws, size_t ws_size,
                              hipStream_t stream) {
    const int*   rows = (const int*)d_in[0];
    const int*   cols = (const int*)d_in[1];
    const float* vals = (const float*)d_in[2];
    const float* ue   = (const float*)d_in[3];
    const float* ie   = (const float*)d_in[4];
    const float* Wc   = (const float*)d_in[5];
    const float* bc   = (const float*)d_in[6];
    const float* We   = (const float*)d_in[7];
    const float* be   = (const float*)d_in[8];
    float* out = (float*)d_out;

    // ws layout (~87 MB). cnt/cur (build-only) overlap ebf (concat runs after).
    unsigned short* ebf = (unsigned short*)d_ws;            // NN*D bf16 (38.4MB)
    unsigned short* sbf = ebf + (size_t)NN * D;             // NN*D bf16 (38.4MB)
    int*   cnt    = (int*)d_ws;                             // NN (build only)
    int*   cur    = cnt + NN;                               // NN (build only)
    int*   rowptr = (int*)(sbf + (size_t)NN * D);           // NN+1
    int*   bsum   = rowptr + NN + 1;                        // 512
    long long* ecv = (long long*)(bsum + 512);              // NNZE (9.6MB)

    const int NB_SCAN = (NN + 1023) / 1024;  // 293

    // ---- build CSR ----
    hipMemsetAsync(cnt, 0, (size_t)NN * sizeof(int), stream);
    k_hist<<<(NNZE + 255) / 256, 256, 0, stream>>>(rows, cnt);
    k_scan1<<<NB_SCAN, 1024, 0, stream>>>(cnt, rowptr, bsum);
    k_scan2<<<1, 512, 0, stream>>>(bsum, NB_SCAN);
    k_scan3<<<NB_SCAN, 1024, 0, stream>>>(rowptr, bsum, cur);
    k_scatter<<<(NNZE + 255) / 256, 256, 0, stream>>>(rows, cols, vals, cur, ecv);

    // ---- embeddings (also initializes ebf; must follow scatter) ----
    k_concat<<<(NN * 16 + 255) / 256, 256, 0, stream>>>(ue, ie, out, ebf);

    const int GB_SPMM = (NN * 16 + 255) / 256;   // 16 lanes per row
    const int GB_DENSE = (NN + 63) / 64;
    for (int l = 0; l < 3; l++) {
        k_spmm<<<GB_SPMM, 256, 0, stream>>>(rowptr, ecv, ebf, sbf);
        k_dense<<<GB_DENSE, 256, 0, stream>>>(
            sbf, ebf, Wc + l * 4096, bc + l * 64,
            We + l * 4096, be + l * 64, out + (l + 1) * 64);
    }
}

// Round 13
// 355.340 us; speedup vs baseline: 1.1006x; 1.1006x over previous
//
#include <hip/hip_runtime.h>

#define NU 100000
#define NI 200000
#define NN 300000
#define NNZE 1200000
#define D 64
#define OS 256   // (L+1)*D output row stride

typedef __attribute__((ext_vector_type(8))) short s16x8;
typedef __attribute__((ext_vector_type(4))) float f32x4;

__device__ __forceinline__ float bf2f(unsigned short u) {
    return __uint_as_float(((unsigned int)u) << 16);
}
__device__ __forceinline__ unsigned short f2bf(float f) {
    unsigned int u = __float_as_uint(f);
    u = (u + 0x7FFF + ((u >> 16) & 1)) >> 16;   // RNE
    return (unsigned short)u;
}

// ---------------- concat -> out chunk0 (fp32, nt) + ebf (bf16 activation) ----
__global__ void k_concat(const float* __restrict__ ue, const float* __restrict__ ie,
                         float* __restrict__ out, unsigned short* __restrict__ ebf) {
    int idx = blockIdx.x * blockDim.x + threadIdx.x;
    if (idx >= NN * 16) return;
    int n = idx >> 4, c = idx & 15;
    float4 v;
    if (n < NU) v = ((const float4*)(ue + (size_t)n * D))[c];
    else        v = ((const float4*)(ie + (size_t)(n - NU) * D))[c];
    f32x4 vv = {v.x, v.y, v.z, v.w};
    __builtin_nontemporal_store(vv, (f32x4*)(out + (size_t)n * OS) + c);
    ushort4 b;
    b.x = f2bf(v.x); b.y = f2bf(v.y); b.z = f2bf(v.z); b.w = f2bf(v.w);
    *(ushort4*)(ebf + (size_t)n * D + c * 4) = b;
}

// ---------------- CSR build ----------------
__global__ void k_hist(const int* __restrict__ rows, int* __restrict__ cnt) {
    int e = blockIdx.x * blockDim.x + threadIdx.x;
    if (e < NNZE) atomicAdd(&cnt[rows[e]], 1);
}

__global__ void k_scan1(const int* __restrict__ cnt, int* __restrict__ rowptr,
                        int* __restrict__ bsum) {
    __shared__ int s[1024];
    int t = threadIdx.x, g = blockIdx.x * 1024 + t;
    int x = (g < NN) ? cnt[g] : 0;
    s[t] = x;
    __syncthreads();
    for (int off = 1; off < 1024; off <<= 1) {
        int y = (t >= off) ? s[t - off] : 0;
        __syncthreads();
        s[t] += y;
        __syncthreads();
    }
    if (g < NN) rowptr[g + 1] = s[t];
    if (t == 1023) bsum[blockIdx.x] = s[1023];
}

__global__ void k_scan2(int* __restrict__ bsum, int nb) {
    __shared__ int s[512];
    int t = threadIdx.x;
    int x = (t < nb) ? bsum[t] : 0;
    s[t] = x;
    __syncthreads();
    for (int off = 1; off < 512; off <<= 1) {
        int y = (t >= off) ? s[t - off] : 0;
        __syncthreads();
        s[t] += y;
        __syncthreads();
    }
    if (t < nb) bsum[t] = s[t];
}

__global__ void k_scan3(int* __restrict__ rowptr, const int* __restrict__ bsum,
                        int* __restrict__ cur) {
    int t = threadIdx.x, g = blockIdx.x * 1024 + t;
    if (g < NN) {
        int off = (blockIdx.x > 0) ? bsum[blockIdx.x - 1] : 0;
        int v = rowptr[g + 1] + off;
        rowptr[g + 1] = v;
        if (g + 1 < NN) cur[g + 1] = v;
    }
    if (g == 0) { rowptr[0] = 0; cur[0] = 0; }
}

__global__ void k_scatter(const int* __restrict__ rows, const int* __restrict__ cols,
                          const float* __restrict__ vals, int* __restrict__ cur,
                          long long* __restrict__ ecv) {
    int e = blockIdx.x * blockDim.x + threadIdx.x;
    if (e >= NNZE) return;
    int r = rows[e];
    int pos = atomicAdd(&cur[r], 1);
    unsigned long long packed = (unsigned int)cols[e]
        | ((unsigned long long)(unsigned int)__float_as_int(vals[e]) << 32);
    ecv[pos] = (long long)packed;
}

// ---------------- fused layer: SpMM (gather, LDS) + MFMA dense ---------------
// Reads ebf_in (read-only this layer), writes ebf_out (double-buffered).
__global__ __launch_bounds__(256) void k_fused(
    const int* __restrict__ rowptr, const long long* __restrict__ ecv,
    const unsigned short* __restrict__ ebf_in, unsigned short* __restrict__ ebf_out,
    const float* __restrict__ Wc, const float* __restrict__ bc,
    const float* __restrict__ We, const float* __restrict__ be,
    float* __restrict__ outN) {
    __shared__ unsigned short sWT[2][64 * 64];  // W^T [n][k] bf16, XOR-swizzled
    __shared__ unsigned short sS[64 * 64];      // side tile [row][k] bf16, swizzled

    int tid = threadIdx.x;
    int n0 = blockIdx.x * 64;

    // stage both W matrices transposed->bf16 into LDS
    #pragma unroll
    for (int m = 0; m < 2; m++) {
        const float* W = m ? We : Wc;
        int base = tid * 16;
        int k = base >> 6, n = base & 63;
        #pragma unroll
        for (int i = 0; i < 4; i++) {
            float4 v = *(const float4*)(W + k * 64 + n + i * 4);
            #pragma unroll
            for (int j = 0; j < 4; j++) {
                int col = n + i * 4 + j;
                int byteoff = (col * 128 + k * 2) ^ ((col & 7) << 4);
                float fv = (j == 0) ? v.x : (j == 1) ? v.y : (j == 2) ? v.z : v.w;
                *(unsigned short*)((char*)&sWT[m][0] + byteoff) = f2bf(fv);
            }
        }
    }

    // SpMM phase: group = tid>>4 handles rows n0+group*4 .. +3
    {
        int grp = tid >> 4, lane = tid & 15;
        #pragma unroll
        for (int rr = 0; rr < 4; rr++) {
            int lrow = grp * 4 + rr;
            int row = n0 + lrow;
            float a0 = 0.f, a1 = 0.f, a2 = 0.f, a3 = 0.f;
            if (row < NN) {
                int beg = rowptr[row], end = rowptr[row + 1];
                for (int i = beg; i < end; i += 8) {
                    unsigned long long e[8];
                    e[0] = (unsigned long long)ecv[i];
                    #pragma unroll
                    for (int k = 1; k < 8; k++)
                        e[k] = (i + k < end) ? (unsigned long long)ecv[i + k] : 0ull;
                    ushort4 gg[8];
                    float v[8];
                    #pragma unroll
                    for (int k = 0; k < 8; k++) {
                        int c = (int)(e[k] & 0xFFFFFFFFu);
                        v[k] = __int_as_float((int)(e[k] >> 32));
                        gg[k] = *(const ushort4*)(ebf_in + (size_t)c * D + lane * 4);
                    }
                    #pragma unroll
                    for (int k = 0; k < 8; k++) {
                        a0 += v[k] * bf2f(gg[k].x);
                        a1 += v[k] * bf2f(gg[k].y);
                        a2 += v[k] * bf2f(gg[k].z);
                        a3 += v[k] * bf2f(gg[k].w);
                    }
                }
            }
            ushort4 r;
            r.x = f2bf(a0); r.y = f2bf(a1); r.z = f2bf(a2); r.w = f2bf(a3);
            int byteoff = (lrow * 128 + lane * 8) ^ ((lrow & 7) << 4);
            *(ushort4*)((char*)&sS[0] + byteoff) = r;
        }
    }

    int wid = tid >> 6, lane = tid & 63;
    int lg = lane >> 4, lr = lane & 15;

    int rowA = n0 + wid * 16 + lr;
    int rowAc = rowA < NN ? rowA : NN - 1;
    size_t abase = (size_t)rowAc * D;
    s16x8 ef[2];
    ef[0] = *(const s16x8*)(ebf_in + abase + lg * 8);
    ef[1] = *(const s16x8*)(ebf_in + abase + 32 + lg * 8);

    f32x4 acc[4];
    #pragma unroll
    for (int c = 0; c < 4; c++) {
        float bj = bc[c * 16 + lr] + be[c * 16 + lr];
        acc[c] = (f32x4){bj, bj, bj, bj};
    }

    __syncthreads();

    // A-fragments from the LDS side tile (swizzled, 2-way conflict max)
    int lrowA = wid * 16 + lr;
    s16x8 sf[2], wf[2];
    #pragma unroll
    for (int kb = 0; kb < 2; kb++) {
        int byteoff = (lrowA * 128 + (kb * 32 + lg * 8) * 2) ^ ((lrowA & 7) << 4);
        sf[kb] = *(const s16x8*)((const char*)&sS[0] + byteoff);
        #pragma unroll
        for (int j = 0; j < 8; j++) {
            float p = bf2f((unsigned short)sf[kb][j]) * bf2f((unsigned short)ef[kb][j]);
            wf[kb][j] = (short)f2bf(p);
        }
    }

    #pragma unroll
    for (int c = 0; c < 4; c++) {
        #pragma unroll
        for (int kb = 0; kb < 2; kb++) {
            int row = c * 16 + lr;
            int byteoff = (row * 128 + (kb * 32 + lg * 8) * 2) ^ ((row & 7) << 4);
            s16x8 bWc = *(const s16x8*)((const char*)&sWT[0][0] + byteoff);
            s16x8 bWe = *(const s16x8*)((const char*)&sWT[1][0] + byteoff);
            acc[c] = __builtin_amdgcn_mfma_f32_16x16x32_bf16(sf[kb], bWc, acc[c], 0, 0, 0);
            acc[c] = __builtin_amdgcn_mfma_f32_16x16x32_bf16(wf[kb], bWe, acc[c], 0, 0, 0);
        }
    }

    float o[4][4];
    float ssq[4] = {0.f, 0.f, 0.f, 0.f};
    #pragma unroll
    for (int c = 0; c < 4; c++) {
        #pragma unroll
        for (int r = 0; r < 4; r++) {
            float x = acc[c][r];
            float y = (x > 0.f) ? x : 0.2f * x;
            o[c][r] = y;
            ssq[r] += y * y;
        }
    }
    #pragma unroll
    for (int r = 0; r < 4; r++) {
        ssq[r] += __shfl_xor(ssq[r], 1);
        ssq[r] += __shfl_xor(ssq[r], 2);
        ssq[r] += __shfl_xor(ssq[r], 4);
        ssq[r] += __shfl_xor(ssq[r], 8);
    }
    #pragma unroll
    for (int r = 0; r < 4; r++) {
        int row = n0 + wid * 16 + lg * 4 + r;
        if (row < NN) {
            float sc = 1.0f / fmaxf(sqrtf(ssq[r]), 1e-12f);
            #pragma unroll
            for (int c = 0; c < 4; c++) {
                __builtin_nontemporal_store(o[c][r] * sc,
                                            &outN[(size_t)row * OS + c * 16 + lr]);
                ebf_out[(size_t)row * D + c * 16 + lr] = f2bf(o[c][r]);
            }
        }
    }
}

extern "C" void kernel_launch(void* const* d_in, const int* in_sizes, int n_in,
                              void* d_out, int out_size, void* d_ws, size_t ws_size,
                              hipStream_t stream) {
    const int*   rows = (const int*)d_in[0];
    const int*   cols = (const int*)d_in[1];
    const float* vals = (const float*)d_in[2];
    const float* ue   = (const float*)d_in[3];
    const float* ie   = (const float*)d_in[4];
    const float* Wc   = (const float*)d_in[5];
    const float* bc   = (const float*)d_in[6];
    const float* We   = (const float*)d_in[7];
    const float* be   = (const float*)d_in[8];
    float* out = (float*)d_out;

    // ws layout (~87 MB): double-buffered ebf + CSR.
    unsigned short* eb0 = (unsigned short*)d_ws;            // NN*D bf16 (38.4MB)
    unsigned short* eb1 = eb0 + (size_t)NN * D;             // NN*D bf16 (38.4MB)
    int*   cnt    = (int*)d_ws;                             // NN (build only)
    int*   cur    = cnt + NN;                               // NN (build only)
    int*   rowptr = (int*)(eb1 + (size_t)NN * D);           // NN+1
    int*   bsum   = rowptr + NN + 1;                        // 512
    long long* ecv = (long long*)(bsum + 512);              // NNZE (9.6MB)

    const int NB_SCAN = (NN + 1023) / 1024;  // 293

    // ---- build CSR ----
    hipMemsetAsync(cnt, 0, (size_t)NN * sizeof(int), stream);
    k_hist<<<(NNZE + 255) / 256, 256, 0, stream>>>(rows, cnt);
    k_scan1<<<NB_SCAN, 1024, 0, stream>>>(cnt, rowptr, bsum);
    k_scan2<<<1, 512, 0, stream>>>(bsum, NB_SCAN);
    k_scan3<<<NB_SCAN, 1024, 0, stream>>>(rowptr, bsum, cur);
    k_scatter<<<(NNZE + 255) / 256, 256, 0, stream>>>(rows, cols, vals, cur, ecv);

    // ---- embeddings (also initializes eb0; must follow scatter) ----
    k_concat<<<(NN * 16 + 255) / 256, 256, 0, stream>>>(ue, ie, out, eb0);

    const int GB_FUSED = (NN + 63) / 64;
    unsigned short* eb[2] = {eb0, eb1};
    for (int l = 0; l < 3; l++) {
        k_fused<<<GB_FUSED, 256, 0, stream>>>(
            rowptr, ecv, eb[l & 1], eb[(l + 1) & 1],
            Wc + l * 4096, bc + l * 64,
            We + l * 4096, be + l * 64, out + (l + 1) * 64);
    }
}